// Round 7
// baseline (250.617 us; speedup 1.0000x reference)
//
#include <hip/hip_runtime.h>
#include <math.h>

#define N 4096
#define IN_F 256
#define OUT_F 512
#define H 8
#define D 64
#define NEG 0.2f
#define JC 1024  // j range per attn block (grid.z = 4)

typedef __attribute__((ext_vector_type(8))) short bf16x8;
typedef __attribute__((ext_vector_type(4))) float f32x4;

__device__ __forceinline__ float leaky(float x) { return fmaxf(x, NEG * x); }

__device__ __forceinline__ unsigned short f2bf(float x) {
    union { float f; unsigned u; } v; v.f = x;
    unsigned r = v.u + 0x7fff + ((v.u >> 16) & 1);  // RNE
    return (unsigned short)(r >> 16);
}
__device__ __forceinline__ float bf2f(unsigned short b) {
    union { float f; unsigned u; } v; v.u = ((unsigned)b) << 16; return v.f;
}

__device__ __forceinline__ unsigned fmap(float x) {
    union { float f; unsigned u; } v; v.f = x;
    return (v.u & 0x80000000u) ? ~v.u : (v.u | 0x80000000u);
}
__device__ __forceinline__ float funmap(unsigned m) {
    union { float f; unsigned u; } v;
    v.u = (m & 0x80000000u) ? (m & 0x7fffffffu) : ~m;
    return v.f;
}

__device__ __forceinline__ void dma16(const void* g, void* l) {
    __builtin_amdgcn_global_load_lds((const __attribute__((address_space(1))) void*)g,
                                     (__attribute__((address_space(3))) void*)l, 16, 0, 0);
}

// ==================== BIG PATH ====================

// ---- K0: per-row prep. Block i: A row -> Abf(bf16) + rmax; inp row -> hi/lo bf16;
// W row (i<OUT_F) -> hi/lo bf16.
__global__ __launch_bounds__(256) void k_prep(const float* __restrict__ A,
                                              const float* __restrict__ inp,
                                              const float* __restrict__ W,
                                              unsigned short* __restrict__ Abf,
                                              float* __restrict__ rmax,
                                              unsigned short* __restrict__ inpH,
                                              unsigned short* __restrict__ inpL,
                                              unsigned short* __restrict__ WH,
                                              unsigned short* __restrict__ WL) {
    const int i = blockIdx.x, t = threadIdx.x;
    const float* row = &A[(size_t)i * N];
    unsigned short* dst = &Abf[(size_t)i * N];
    float m = -1e30f;
    for (int j = t * 4; j < N; j += 256 * 4) {
        float4 v = *(const float4*)&row[j];
        m = fmaxf(fmaxf(fmaxf(m, v.x), fmaxf(v.y, v.z)), v.w);
        ushort4 b = {f2bf(v.x), f2bf(v.y), f2bf(v.z), f2bf(v.w)};
        *(ushort4*)&dst[j] = b;
    }
    for (int off = 32; off; off >>= 1) m = fmaxf(m, __shfl_down(m, off, 64));
    __shared__ float red[4];
    if ((t & 63) == 0) red[t >> 6] = m;
    __syncthreads();
    if (t == 0) rmax[i] = fmaxf(fmaxf(red[0], red[1]), fmaxf(red[2], red[3]));

    // inp row: one element per thread
    {
        float v = inp[(size_t)i * IN_F + t];
        unsigned short hi = f2bf(v);
        inpH[(size_t)i * IN_F + t] = hi;
        inpL[(size_t)i * IN_F + t] = f2bf(v - bf2f(hi));
    }
    if (i < OUT_F) {
        float v = W[(size_t)i * IN_F + t];
        unsigned short hi = f2bf(v);
        WH[(size_t)i * IN_F + t] = hi;
        WL[(size_t)i * IN_F + t] = f2bf(v - bf2f(hi));
    }
}

// ---- K1: h = inp @ W^T via split-bf16 MFMA, LDS-free K-loop, direct fragment loads.
// Block = (64 i, head); wave w owns rows w*16..+15, all 64 o. grid (64, 8).
__global__ __launch_bounds__(256) void k_gemm(const unsigned short* __restrict__ inpH,
                                              const unsigned short* __restrict__ inpL,
                                              const unsigned short* __restrict__ WH,
                                              const unsigned short* __restrict__ WL,
                                              const float* __restrict__ a_left,
                                              unsigned short* __restrict__ hbT,
                                              float* __restrict__ s,
                                              unsigned* __restrict__ smaxU) {
    __shared__ unsigned short h_st[64][72];
    __shared__ float s_red[64];
    const int t = threadIdx.x, bx = blockIdx.x, head = blockIdx.y;
    const int wave = t >> 6, lane = t & 63, quad = lane >> 4, li = lane & 15;
    const int i0 = bx * 64;

    const unsigned short* pAH = inpH + (size_t)(i0 + wave * 16 + li) * IN_F + quad * 8;
    const unsigned short* pAL = inpL + (size_t)(i0 + wave * 16 + li) * IN_F + quad * 8;
    const unsigned short* pBH[4];
    const unsigned short* pBL[4];
#pragma unroll
    for (int ot = 0; ot < 4; ++ot) {
        pBH[ot] = WH + (size_t)(head * 64 + ot * 16 + li) * IN_F + quad * 8;
        pBL[ot] = WL + (size_t)(head * 64 + ot * 16 + li) * IN_F + quad * 8;
    }

    f32x4 acc[4] = {};
#pragma unroll
    for (int ks = 0; ks < 8; ++ks) {  // K = 8 x 32
        bf16x8 ah = *(const bf16x8*)(pAH + ks * 32);
        bf16x8 al = *(const bf16x8*)(pAL + ks * 32);
#pragma unroll
        for (int ot = 0; ot < 4; ++ot) {
            bf16x8 bh = *(const bf16x8*)(pBH[ot] + ks * 32);
            bf16x8 bl = *(const bf16x8*)(pBL[ot] + ks * 32);
            acc[ot] = __builtin_amdgcn_mfma_f32_16x16x32_bf16(ah, bh, acc[ot], 0, 0, 0);
            acc[ot] = __builtin_amdgcn_mfma_f32_16x16x32_bf16(al, bh, acc[ot], 0, 0, 0);
            acc[ot] = __builtin_amdgcn_mfma_f32_16x16x32_bf16(ah, bl, acc[ot], 0, 0, 0);
        }
    }

    // scores: row i = i0 + wave*16 + quad*4 + r; col o = ot*16 + li
    float aLv[4];
#pragma unroll
    for (int ot = 0; ot < 4; ++ot) aLv[ot] = a_left[head * D + ot * 16 + li];
#pragma unroll
    for (int r = 0; r < 4; ++r) {
        float sp = acc[0][r] * aLv[0] + acc[1][r] * aLv[1] + acc[2][r] * aLv[2] + acc[3][r] * aLv[3];
        sp += __shfl_xor(sp, 1); sp += __shfl_xor(sp, 2);
        sp += __shfl_xor(sp, 4); sp += __shfl_xor(sp, 8);
        if (li == 0) {
            int rloc = wave * 16 + quad * 4 + r;
            s[head * N + i0 + rloc] = sp;
            s_red[rloc] = sp;
        }
    }
    // h -> bf16 LDS for transpose
#pragma unroll
    for (int ot = 0; ot < 4; ++ot)
#pragma unroll
        for (int r = 0; r < 4; ++r)
            h_st[wave * 16 + quad * 4 + r][ot * 16 + li] = f2bf(acc[ot][r]);
    __syncthreads();
    if (t < 64) {
        float m = s_red[t];
        for (int off = 32; off; off >>= 1) m = fmaxf(m, __shfl_down(m, off, 64));
        if (t == 0) atomicMax(&smaxU[head], fmap(m));
    }
    {
        const int d = t >> 2, iq = (t & 3) * 16;
        unsigned short us[16];
#pragma unroll
        for (int k = 0; k < 16; ++k) us[k] = h_st[iq + k][d];
        unsigned short* dst = &hbT[((size_t)(head * D + d)) * N + i0 + iq];
#pragma unroll
        for (int q = 0; q < 4; ++q) {
            ushort4 v = {us[q * 4 + 0], us[q * 4 + 1], us[q * 4 + 2], us[q * 4 + 3]};
            *(ushort4*)&dst[q * 4] = v;
        }
    }
}

// ---- K2: fused attention, barrier-free K-loop, direct L2 fragment loads.
// Block = (128 i, head, j-quarter); grid 32 x 8 x 4 = 1024 blocks (4/CU).
__global__ __launch_bounds__(256, 4) void k_attn(const unsigned short* __restrict__ Abf,
                                                 const unsigned short* __restrict__ hbT,
                                                 const float* __restrict__ s,
                                                 const unsigned* __restrict__ smaxU,
                                                 const float* __restrict__ rmax,
                                                 float* __restrict__ out,
                                                 float* __restrict__ Z) {
    __shared__ float s_ch[JC];  // 4 KB, read-only after one sync

    const int t = threadIdx.x;
    const int i0 = blockIdx.x * 128;
    const int head = blockIdx.y;
    const int j0 = blockIdx.z * JC;
    const int lane = t & 63, wave = t >> 6, quad = lane >> 4, li = lane & 15;

    *(float4*)&s_ch[t * 4] = *(const float4*)&s[head * N + j0 + t * 4];

    const float smx = funmap(smaxU[head]);
    float s_i[2], nmb[2];
#pragma unroll
    for (int is = 0; is < 2; ++is) {
        int row = i0 + wave * 32 + is * 16 + li;
        float sv = s[head * N + row];
        s_i[is] = sv;
        nmb[is] = -(leaky(sv + smx) + rmax[row]);
    }
    __syncthreads();

    const unsigned short* pA[2];
#pragma unroll
    for (int is = 0; is < 2; ++is)
        pA[is] = Abf + (size_t)(i0 + wave * 32 + is * 16 + li) * N + j0 + quad * 8;
    const unsigned short* pH[4];
#pragma unroll
    for (int db = 0; db < 4; ++db)
        pH[db] = hbT + (size_t)(head * D + db * 16 + li) * N + j0 + quad * 8;

    f32x4 acc[2][4] = {};
    f32x4 accz[2] = {};
    bf16x8 onesb;
#pragma unroll
    for (int i = 0; i < 8; ++i) onesb[i] = 0x3F80;

    for (int tg = 0; tg < JC / 128; ++tg) {  // 8 groups of 4 tiles
#pragma unroll
        for (int u = 0; u < 4; ++u) {
            bf16x8 hf[4];
#pragma unroll
            for (int db = 0; db < 4; ++db) hf[db] = *(const bf16x8*)(pH[db] + u * 32);
            uint4 au[2];
#pragma unroll
            for (int is = 0; is < 2; ++is) au[is] = *(const uint4*)(pA[is] + u * 32);
            float4 s0 = *(const float4*)&s_ch[tg * 128 + u * 32 + quad * 8];
            float4 s1 = *(const float4*)&s_ch[tg * 128 + u * 32 + quad * 8 + 4];
            float sv[8] = {s0.x, s0.y, s0.z, s0.w, s1.x, s1.y, s1.z, s1.w};
#pragma unroll
            for (int is = 0; is < 2; ++is) {
                unsigned auv[4] = {au[is].x, au[is].y, au[is].z, au[is].w};
                union { bf16x8 v; unsigned u[4]; } P;
                const float si = s_i[is], nm = nmb[is];
#pragma unroll
                for (int w = 0; w < 4; ++w) {
                    float aLo = __uint_as_float(auv[w] << 16);
                    float aHi = __uint_as_float(auv[w] & 0xffff0000u);
                    float x0 = si + sv[2 * w + 0];
                    float x1 = si + sv[2 * w + 1];
                    float l0 = fmaxf(x0, NEG * x0);
                    float l1 = fmaxf(x1, NEG * x1);
                    float e0 = __expf(l0 + (aLo + nm));
                    float e1 = __expf(l1 + (aHi + nm));
                    unsigned r0 = __float_as_uint(e0) + 0x8000u;
                    unsigned r1 = __float_as_uint(e1) + 0x8000u;
                    P.u[w] = __builtin_amdgcn_perm(r1, r0, 0x07060302u);
                }
#pragma unroll
                for (int db = 0; db < 4; ++db)
                    acc[is][db] = __builtin_amdgcn_mfma_f32_16x16x32_bf16(P.v, hf[db], acc[is][db], 0, 0, 0);
                accz[is] = __builtin_amdgcn_mfma_f32_16x16x32_bf16(P.v, onesb, accz[is], 0, 0, 0);
            }
        }
        pA[0] += 128; pA[1] += 128;
        pH[0] += 128; pH[1] += 128; pH[2] += 128; pH[3] += 128;
    }

#pragma unroll
    for (int is = 0; is < 2; ++is) {
        int rowbase = i0 + wave * 32 + is * 16 + quad * 4;
#pragma unroll
        for (int r = 0; r < 4; ++r) {
            float* op = &out[(size_t)(rowbase + r) * OUT_F + head * D];
#pragma unroll
            for (int db = 0; db < 4; ++db) atomicAdd(&op[db * 16 + li], acc[is][db][r]);
        }
        if (li == 0) {
#pragma unroll
            for (int r = 0; r < 4; ++r) atomicAdd(&Z[head * N + rowbase + r], accz[is][r]);
        }
    }
}

// ---- K3: normalize
__global__ __launch_bounds__(256) void k_norm(float* __restrict__ out,
                                              const float* __restrict__ Z) {
    int idx = blockIdx.x * 256 + threadIdx.x;
    int i = idx >> 9, hd = idx & 511, hh = hd >> 6;
    out[idx] = out[idx] / Z[hh * N + i];
}

// ==================== FALLBACK PATH (proven R4/R6 f32 chain) ====================

__global__ __launch_bounds__(256, 4) void k_gemm_f(const float* __restrict__ inp,
                                                   const float* __restrict__ W,
                                                   const float* __restrict__ a_left,
                                                   unsigned short* __restrict__ hbT,
                                                   float* __restrict__ s,
                                                   unsigned* __restrict__ smaxU) {
    __shared__ float As[64][36];
    __shared__ float Bs[64][68];
    __shared__ unsigned short h_st[32][72];
    __shared__ float s_red[32];

    const int t = threadIdx.x;
    const int bi = blockIdx.x;
    const int head = blockIdx.y;
    const int iy = t >> 4, ox = t & 15;
    const int iA = t >> 3, kA = (t & 7) * 8;
    const int oB = t >> 2, kB = (t & 3) * 16;

    float4 pa[2], pb[4];
    auto loadrk = [&](int k0) {
        const float* ip = &inp[(size_t)(bi * 32 + iA) * IN_F + k0 + kA];
        const float* wp = &W[(size_t)(head * 64 + oB) * IN_F + k0 + kB];
#pragma unroll
        for (int q = 0; q < 2; ++q) pa[q] = *(const float4*)&ip[q * 4];
#pragma unroll
        for (int q = 0; q < 4; ++q) pb[q] = *(const float4*)&wp[q * 4];
    };
    loadrk(0);

    float acc[2][4] = {};
    for (int k0 = 0; k0 < IN_F; k0 += 64) {
        __syncthreads();
#pragma unroll
        for (int q = 0; q < 2; ++q)
#pragma unroll
            for (int j = 0; j < 4; ++j) As[kA + q * 4 + j][iA] = ((const float*)&pa[q])[j];
#pragma unroll
        for (int q = 0; q < 4; ++q)
#pragma unroll
            for (int j = 0; j < 4; ++j) Bs[kB + q * 4 + j][oB] = ((const float*)&pb[q])[j];
        __syncthreads();
        if (k0 + 64 < IN_F) loadrk(k0 + 64);
#pragma unroll
        for (int k = 0; k < 64; ++k) {
            float2 a2 = *(const float2*)&As[k][iy * 2];
            float4 b4 = *(const float4*)&Bs[k][ox * 4];
            float a[2] = {a2.x, a2.y};
            float b[4] = {b4.x, b4.y, b4.z, b4.w};
#pragma unroll
            for (int r = 0; r < 2; ++r)
#pragma unroll
                for (int c = 0; c < 4; ++c) acc[r][c] = fmaf(a[r], b[c], acc[r][c]);
        }
    }
    float aL[4];
#pragma unroll
    for (int c = 0; c < 4; ++c) aL[c] = a_left[head * D + ox * 4 + c];
#pragma unroll
    for (int r = 0; r < 2; ++r) {
        float sp = acc[r][0] * aL[0] + acc[r][1] * aL[1] + acc[r][2] * aL[2] + acc[r][3] * aL[3];
        sp += __shfl_xor(sp, 1); sp += __shfl_xor(sp, 2);
        sp += __shfl_xor(sp, 4); sp += __shfl_xor(sp, 8);
        if (ox == 0) {
            s[head * N + bi * 32 + iy * 2 + r] = sp;
            s_red[iy * 2 + r] = sp;
        }
    }
    __syncthreads();
    if (t < 32) {
        float m = s_red[t];
        for (int off = 16; off; off >>= 1) m = fmaxf(m, __shfl_down(m, off, 64));
        if (t == 0) atomicMax(&smaxU[head], fmap(m));
    }
#pragma unroll
    for (int r = 0; r < 2; ++r) {
        ushort4 v;
        v.x = f2bf(acc[r][0]); v.y = f2bf(acc[r][1]);
        v.z = f2bf(acc[r][2]); v.w = f2bf(acc[r][3]);
        *(ushort4*)&h_st[iy * 2 + r][ox * 4] = v;
    }
    __syncthreads();
    {
        const int d = t >> 2, iq = (t & 3) * 8;
        unsigned short us[8];
#pragma unroll
        for (int k = 0; k < 8; ++k) us[k] = h_st[iq + k][d];
        unsigned short* dst = &hbT[((size_t)(head * D + d)) * N + bi * 32 + iq];
#pragma unroll
        for (int q = 0; q < 2; ++q) {
            ushort4 v = {us[q * 4 + 0], us[q * 4 + 1], us[q * 4 + 2], us[q * 4 + 3]};
            *(ushort4*)&dst[q * 4] = v;
        }
    }
}

__global__ __launch_bounds__(256) void k_rowmax(const float* __restrict__ A,
                                                float* __restrict__ rmax) {
    int i = blockIdx.x;
    const float* row = &A[(size_t)i * N];
    float m = -1e30f;
    for (int j = threadIdx.x * 4; j < N; j += 256 * 4) {
        float4 v = *(const float4*)&row[j];
        m = fmaxf(fmaxf(fmaxf(m, v.x), fmaxf(v.y, v.z)), v.w);
    }
    for (int off = 32; off; off >>= 1) m = fmaxf(m, __shfl_down(m, off, 64));
    __shared__ float red[4];
    if ((threadIdx.x & 63) == 0) red[threadIdx.x >> 6] = m;
    __syncthreads();
    if (threadIdx.x == 0) rmax[i] = fmaxf(fmaxf(red[0], red[1]), fmaxf(red[2], red[3]));
}

#define JCF 2048
__global__ __launch_bounds__(256, 4) void k_attn_f(const float* __restrict__ A,
                                                   const unsigned short* __restrict__ hbT,
                                                   const float* __restrict__ s,
                                                   const unsigned* __restrict__ smaxU,
                                                   const float* __restrict__ rmax,
                                                   float* __restrict__ out,
                                                   float* __restrict__ Z) {
    __shared__ float A_stf[64 * 16 * 4];
    __shared__ unsigned short hT_stf[64 * 8 * 8];
    __shared__ float s_ch[JCF];

    const int t = threadIdx.x;
    const int i0 = blockIdx.x * 64;
    const int head = blockIdx.y;
    const int j0 = blockIdx.z * JCF;
    const int lane = t & 63, wave = t >> 6, quad = lane >> 4, li = lane & 15;
    const int iw = wave * 16;
    const int myrow = i0 + iw + li;

#pragma unroll
    for (int q = 0; q < 2; ++q) {
        int idx = q * 256 + t;
        *(float4*)&s_ch[idx * 4] = *(const float4*)&s[head * N + j0 + idx * 4];
    }
    const float s_i = s[head * N + myrow];
    const float mb = leaky(s_i + funmap(smaxU[head])) + rmax[myrow];

    const float* gA[4]; void* lA[4];
#pragma unroll
    for (int q = 0; q < 4; ++q) {
        int slot = q * 256 + t;
        int r = slot >> 4, c4p = slot & 15;
        int c4 = c4p ^ (r & 7);
        gA[q] = &A[(size_t)(i0 + r) * N + j0 + c4 * 4];
        lA[q] = (void*)&A_stf[slot * 4];
    }
    const unsigned short* gH[2]; void* lH[2];
#pragma unroll
    for (int q = 0; q < 2; ++q) {
        int slot = q * 256 + t;
        int r = slot >> 3, u = slot & 7;
        int uc = u ^ (r & 7);
        gH[q] = &hbT[(size_t)head * D * N + (size_t)r * N + j0 + uc * 8];
        lH[q] = (void*)&hT_stf[slot * 8];
    }

    f32x4 acc[4] = {{0, 0, 0, 0}, {0, 0, 0, 0}, {0, 0, 0, 0}, {0, 0, 0, 0}};
    float zsum = 0.f;

    for (int jt = 0; jt < JCF; jt += 64) {
        __syncthreads();
#pragma unroll
        for (int q = 0; q < 4; ++q) dma16(gA[q] + jt, lA[q]);
#pragma unroll
        for (int q = 0; q < 2; ++q) dma16(gH[q] + jt, lH[q]);
        __syncthreads();

#pragma unroll
        for (int kh = 0; kh < 2; ++kh) {
            const int u0 = kh * 8 + quad * 2;
            const int sw = li & 7;
            float4 a0 = *(const float4*)&A_stf[((iw + li) * 16 + (u0 ^ sw)) * 4];
            float4 a1 = *(const float4*)&A_stf[((iw + li) * 16 + ((u0 + 1) ^ sw)) * 4];
            const int jl = kh * 32 + quad * 8;
            float4 s0 = *(const float4*)&s_ch[jt + jl];
            float4 s1 = *(const float4*)&s_ch[jt + jl + 4];
            float av[8] = {a0.x, a0.y, a0.z, a0.w, a1.x, a1.y, a1.z, a1.w};
            float sv[8] = {s0.x, s0.y, s0.z, s0.w, s1.x, s1.y, s1.z, s1.w};
            union { bf16x8 v; unsigned u[4]; } P;
#pragma unroll
            for (int p = 0; p < 4; ++p) {
                float x0 = s_i + sv[2 * p + 0];
                float x1 = s_i + sv[2 * p + 1];
                float w0 = __expf(fmaxf(x0, NEG * x0) + (av[2 * p + 0] - mb));
                float w1 = __expf(fmaxf(x1, NEG * x1) + (av[2 * p + 1] - mb));
                zsum += w0 + w1;
                P.u[p] = ((unsigned)f2bf(w1) << 16) | (unsigned)f2bf(w0);
            }
#pragma unroll
            for (int db = 0; db < 4; ++db) {
                int slotH = (db * 16 + li) * 8 + ((kh * 4 + quad) ^ sw);
                bf16x8 hf = *(const bf16x8*)&hT_stf[slotH * 8];
                acc[db] = __builtin_amdgcn_mfma_f32_16x16x32_bf16(P.v, hf, acc[db], 0, 0, 0);
            }
        }
    }

    zsum += __shfl_xor(zsum, 16);
    zsum += __shfl_xor(zsum, 32);
    if (quad == 0) atomicAdd(&Z[head * N + myrow], zsum);

#pragma unroll
    for (int r = 0; r < 4; ++r) {
        float* op = &out[(size_t)(i0 + iw + quad * 4 + r) * OUT_F + head * D];
#pragma unroll
        for (int db = 0; db < 4; ++db) atomicAdd(&op[db * 16 + li], acc[db][r]);
    }
}

// ==================== launcher ====================

extern "C" void kernel_launch(void* const* d_in, const int* in_sizes, int n_in,
                              void* d_out, int out_size, void* d_ws, size_t ws_size,
                              hipStream_t stream) {
    const float* inp = (const float*)d_in[0];
    const float* A = (const float*)d_in[1];
    const float* W = (const float*)d_in[2];
    const float* a_left = (const float*)d_in[3];
    float* out = (float*)d_out;

    // ws: hbT 4MB | s 128K | Z 128K | smaxU 32B | rmax 16K | @5M inpH 2M | @7M inpL 2M
    //     | @9M WH 256K | @9.25M WL 256K | @10M Abf 32M  => 42MB total
    char* base = (char*)d_ws;
    unsigned short* hbT = (unsigned short*)base;
    float* s = (float*)(base + (size_t)H * D * N * 2);
    float* Z = s + (size_t)H * N;
    unsigned* smaxU = (unsigned*)(Z + (size_t)H * N);
    float* rmax = (float*)(smaxU + 8);
    unsigned short* inpH = (unsigned short*)(base + ((size_t)5 << 20));
    unsigned short* inpL = (unsigned short*)(base + ((size_t)7 << 20));
    unsigned short* WH = (unsigned short*)(base + ((size_t)9 << 20));
    unsigned short* WL = (unsigned short*)(base + ((size_t)9 << 20) + ((size_t)256 << 10));
    unsigned short* Abf = (unsigned short*)(base + ((size_t)10 << 20));
    const bool big = ws_size >= (((size_t)10 << 20) + (size_t)N * N * 2);

    hipMemsetAsync(out, 0, (size_t)N * OUT_F * sizeof(float), stream);
    hipMemsetAsync(Z, 0, (size_t)H * N * sizeof(float) + 8 * sizeof(unsigned), stream);

    if (big) {
        k_prep<<<dim3(N), 256, 0, stream>>>(A, inp, W, Abf, rmax, inpH, inpL, WH, WL);
        k_gemm<<<dim3(N / 64, H), 256, 0, stream>>>(inpH, inpL, WH, WL, a_left, hbT, s, smaxU);
        k_attn<<<dim3(N / 128, H, N / JC), 256, 0, stream>>>(Abf, hbT, s, smaxU, rmax, out, Z);
    } else {
        k_gemm_f<<<dim3(N / 32, H), 256, 0, stream>>>(inp, W, a_left, hbT, s, smaxU);
        k_rowmax<<<dim3(N), 256, 0, stream>>>(A, rmax);
        k_attn_f<<<dim3(N / 64, H, N / JCF), 256, 0, stream>>>(A, hbT, s, smaxU, rmax, out, Z);
    }
    k_norm<<<dim3(N * OUT_F / 256), 256, 0, stream>>>(out, Z);
}

// Round 8
// 225.256 us; speedup vs baseline: 1.1126x; 1.1126x over previous
//
#include <hip/hip_runtime.h>
#include <math.h>

#define N 4096
#define IN_F 256
#define OUT_F 512
#define H 8
#define D 64
#define NEG 0.2f
#define JC 1024  // j range per attn block (grid.z = 4)

typedef __attribute__((ext_vector_type(8))) short bf16x8;
typedef __attribute__((ext_vector_type(4))) float f32x4;

union UB { uint4 u; bf16x8 v; };

__device__ __forceinline__ float leaky(float x) { return fmaxf(x, NEG * x); }

__device__ __forceinline__ unsigned short f2bf(float x) {
    union { float f; unsigned u; } v; v.f = x;
    unsigned r = v.u + 0x7fff + ((v.u >> 16) & 1);  // RNE
    return (unsigned short)(r >> 16);
}
__device__ __forceinline__ float bf2f(unsigned short b) {
    union { float f; unsigned u; } v; v.u = ((unsigned)b) << 16; return v.f;
}

__device__ __forceinline__ unsigned fmap(float x) {
    union { float f; unsigned u; } v; v.f = x;
    return (v.u & 0x80000000u) ? ~v.u : (v.u | 0x80000000u);
}
__device__ __forceinline__ float funmap(unsigned m) {
    union { float f; unsigned u; } v;
    v.u = (m & 0x80000000u) ? (m & 0x7fffffffu) : ~m;
    return v.f;
}

__device__ __forceinline__ void dma16(const void* g, void* l) {
    __builtin_amdgcn_global_load_lds((const __attribute__((address_space(1))) void*)g,
                                     (__attribute__((address_space(3))) void*)l, 16, 0, 0);
}

// ==================== BIG PATH ====================
// Fragment-linear layouts: every MFMA fragment for a wave is a contiguous 1 KB
// block (lane l -> base + l*16B), so all global loads are single coalesced bursts.
//
// AF  [ib(32)][jt(128)][w(4)][is(2)][lane(64)*8 bf16]   : A in bf16, 32 MB
// hbF [head(8)][jt(128)][db(4)][lane(64)*8 bf16]        : h^T bf16, 4 MB
// inpF[g(256)][ks(8)][lane(64)*8 bf16] hi+lo            : 2 MB each
// WF  [gw(32)][ks(8)][lane(64)*8 bf16] hi+lo            : 256 KB each

// ---- K0: per-row prep. Block i: A row -> AF + rmax; inp row -> inpF hi/lo;
// W row (i<OUT_F) -> WF hi/lo.
__global__ __launch_bounds__(256) void k_prep(const float* __restrict__ A,
                                              const float* __restrict__ inp,
                                              const float* __restrict__ W,
                                              unsigned short* __restrict__ AF,
                                              float* __restrict__ rmax,
                                              unsigned short* __restrict__ iFH,
                                              unsigned short* __restrict__ iFL,
                                              unsigned short* __restrict__ WFH,
                                              unsigned short* __restrict__ WFL) {
    const int i = blockIdx.x, t = threadIdx.x;
    const int i0b = i >> 7, w = (i >> 5) & 3, is = (i >> 4) & 1, li = i & 15;
    float m = -1e30f;
#pragma unroll
    for (int q = 0; q < 2; ++q) {
        const int j8 = t + q * 256;           // 16B chunk index within row
        const int j = j8 * 8;
        float4 v0 = *(const float4*)&A[(size_t)i * N + j];
        float4 v1 = *(const float4*)&A[(size_t)i * N + j + 4];
        m = fmaxf(m, fmaxf(fmaxf(fmaxf(v0.x, v0.y), fmaxf(v0.z, v0.w)),
                           fmaxf(fmaxf(v1.x, v1.y), fmaxf(v1.z, v1.w))));
        ushort4 b0 = {f2bf(v0.x), f2bf(v0.y), f2bf(v0.z), f2bf(v0.w)};
        ushort4 b1 = {f2bf(v1.x), f2bf(v1.y), f2bf(v1.z), f2bf(v1.w)};
        const int jt = j >> 5, quad = (j >> 3) & 3;
        unsigned short* dst = AF + ((size_t)(i0b * 128 + jt)) * 4096 +
                              (w * 2 + is) * 512 + (quad * 16 + li) * 8;
        *(ushort4*)dst = b0;
        *(ushort4*)(dst + 4) = b1;
    }
    for (int off = 32; off; off >>= 1) m = fmaxf(m, __shfl_down(m, off, 64));
    __shared__ float red[4];
    if ((t & 63) == 0) red[t >> 6] = m;
    __syncthreads();
    if (t == 0) rmax[i] = fmaxf(fmaxf(red[0], red[1]), fmaxf(red[2], red[3]));

    if (t < 32) {  // inp row -> frag-linear hi/lo
        const int k = t * 8;
        float4 v0 = *(const float4*)&inp[(size_t)i * IN_F + k];
        float4 v1 = *(const float4*)&inp[(size_t)i * IN_F + k + 4];
        float vv[8] = {v0.x, v0.y, v0.z, v0.w, v1.x, v1.y, v1.z, v1.w};
        ushort4 h0, h1, l0, l1;
        unsigned short hs[8], ls[8];
#pragma unroll
        for (int e = 0; e < 8; ++e) {
            hs[e] = f2bf(vv[e]);
            ls[e] = f2bf(vv[e] - bf2f(hs[e]));
        }
        h0 = {hs[0], hs[1], hs[2], hs[3]}; h1 = {hs[4], hs[5], hs[6], hs[7]};
        l0 = {ls[0], ls[1], ls[2], ls[3]}; l1 = {ls[4], ls[5], ls[6], ls[7]};
        size_t dst = ((size_t)(i >> 4) * 8 + (k >> 5)) * 512 + (((k >> 3) & 3) * 16 + (i & 15)) * 8;
        *(ushort4*)(iFH + dst) = h0; *(ushort4*)(iFH + dst + 4) = h1;
        *(ushort4*)(iFL + dst) = l0; *(ushort4*)(iFL + dst + 4) = l1;
    } else if (t >= 64 && t < 96 && i < OUT_F) {  // W row -> frag-linear hi/lo
        const int k = (t - 64) * 8;
        float4 v0 = *(const float4*)&W[(size_t)i * IN_F + k];
        float4 v1 = *(const float4*)&W[(size_t)i * IN_F + k + 4];
        float vv[8] = {v0.x, v0.y, v0.z, v0.w, v1.x, v1.y, v1.z, v1.w};
        unsigned short hs[8], ls[8];
#pragma unroll
        for (int e = 0; e < 8; ++e) {
            hs[e] = f2bf(vv[e]);
            ls[e] = f2bf(vv[e] - bf2f(hs[e]));
        }
        ushort4 h0 = {hs[0], hs[1], hs[2], hs[3]}, h1 = {hs[4], hs[5], hs[6], hs[7]};
        ushort4 l0 = {ls[0], ls[1], ls[2], ls[3]}, l1 = {ls[4], ls[5], ls[6], ls[7]};
        size_t dst = ((size_t)(i >> 4) * 8 + (k >> 5)) * 512 + (((k >> 3) & 3) * 16 + (i & 15)) * 8;
        *(ushort4*)(WFH + dst) = h0; *(ushort4*)(WFH + dst + 4) = h1;
        *(ushort4*)(WFL + dst) = l0; *(ushort4*)(WFL + dst + 4) = l1;
    }
}

// ---- K1: h = inp @ W^T via split-bf16 MFMA, frag-linear coalesced loads.
// Block = (64 i, head); grid (64, 8). Epilogue: s, smax, hbF frag-pack.
__global__ __launch_bounds__(256) void k_gemm(const unsigned short* __restrict__ iFH,
                                              const unsigned short* __restrict__ iFL,
                                              const unsigned short* __restrict__ WFH,
                                              const unsigned short* __restrict__ WFL,
                                              const float* __restrict__ a_left,
                                              unsigned short* __restrict__ hbF,
                                              float* __restrict__ s,
                                              unsigned* __restrict__ smaxU) {
    __shared__ unsigned short h_st[64][72];
    __shared__ float s_red[64];
    const int t = threadIdx.x, bx = blockIdx.x, head = blockIdx.y;
    const int wave = t >> 6, lane = t & 63, quad = lane >> 4, li = lane & 15;
    const int i0 = bx * 64;

    const unsigned short* pAH = iFH + (size_t)(bx * 4 + wave) * 8 * 512 + lane * 8;
    const unsigned short* pAL = iFL + (size_t)(bx * 4 + wave) * 8 * 512 + lane * 8;

    f32x4 acc[4] = {};
#pragma unroll
    for (int ks = 0; ks < 8; ++ks) {
        UB ah, al; ah.u = *(const uint4*)(pAH + ks * 512); al.u = *(const uint4*)(pAL + ks * 512);
#pragma unroll
        for (int ot = 0; ot < 4; ++ot) {
            size_t off = ((size_t)(head * 4 + ot) * 8 + ks) * 512 + lane * 8;
            UB bh, bl; bh.u = *(const uint4*)(WFH + off); bl.u = *(const uint4*)(WFL + off);
            acc[ot] = __builtin_amdgcn_mfma_f32_16x16x32_bf16(ah.v, bh.v, acc[ot], 0, 0, 0);
            acc[ot] = __builtin_amdgcn_mfma_f32_16x16x32_bf16(al.v, bh.v, acc[ot], 0, 0, 0);
            acc[ot] = __builtin_amdgcn_mfma_f32_16x16x32_bf16(ah.v, bl.v, acc[ot], 0, 0, 0);
        }
    }

    // scores: C/D layout row(M)=quad*4+r, col(N)=li -> i = i0+wave*16+quad*4+r, o = ot*16+li
    float aLv[4];
#pragma unroll
    for (int ot = 0; ot < 4; ++ot) aLv[ot] = a_left[head * D + ot * 16 + li];
#pragma unroll
    for (int r = 0; r < 4; ++r) {
        float sp = acc[0][r] * aLv[0] + acc[1][r] * aLv[1] + acc[2][r] * aLv[2] + acc[3][r] * aLv[3];
        sp += __shfl_xor(sp, 1); sp += __shfl_xor(sp, 2);
        sp += __shfl_xor(sp, 4); sp += __shfl_xor(sp, 8);
        if (li == 0) {
            int rloc = wave * 16 + quad * 4 + r;
            s[head * N + i0 + rloc] = sp;
            s_red[rloc] = sp;
        }
    }
#pragma unroll
    for (int ot = 0; ot < 4; ++ot)
#pragma unroll
        for (int r = 0; r < 4; ++r)
            h_st[wave * 16 + quad * 4 + r][ot * 16 + li] = f2bf(acc[ot][r]);
    __syncthreads();
    if (t < 64) {
        float m = s_red[t];
        for (int off = 32; off; off >>= 1) m = fmaxf(m, __shfl_down(m, off, 64));
        if (t == 0) atomicMax(&smaxU[head], fmap(m));
    }
    // hbF frag pack: chunk c -> (jt2, db, lane'); values h[d=db*16+li'][j=jt2*32+quad'*8+jj]
#pragma unroll
    for (int q = 0; q < 2; ++q) {
        const int c = t * 2 + q;
        const int jt2 = c >> 8, db = (c >> 6) & 3, lp = c & 63;
        const int liq = lp & 15, qd = lp >> 4;
        unsigned short us[8];
#pragma unroll
        for (int jj = 0; jj < 8; ++jj) us[jj] = h_st[jt2 * 32 + qd * 8 + jj][db * 16 + liq];
        unsigned short* dst = hbF + ((size_t)(head * 128 + bx * 2 + jt2) * 4 + db) * 512 + lp * 8;
        ushort4 v0 = {us[0], us[1], us[2], us[3]}, v1 = {us[4], us[5], us[6], us[7]};
        *(ushort4*)dst = v0;
        *(ushort4*)(dst + 4) = v1;
    }
}

// ---- K2: fused attention. Barrier-free streaming K-loop, register ping-pong
// prefetch, all loads fragment-contiguous (1 KB/wave). Grid 32 x 8 x 4.
__global__ __launch_bounds__(256, 4) void k_attn(const unsigned short* __restrict__ AF,
                                                 const unsigned short* __restrict__ hbF,
                                                 const float* __restrict__ s,
                                                 const unsigned* __restrict__ smaxU,
                                                 const float* __restrict__ rmax,
                                                 float* __restrict__ out,
                                                 float* __restrict__ Z) {
    __shared__ float s_ch[JC];  // 4 KB, read-only after one sync

    const int t = threadIdx.x;
    const int i0 = blockIdx.x * 128;
    const int head = blockIdx.y;
    const int j0 = blockIdx.z * JC;
    const int lane = t & 63, wave = t >> 6, quad = lane >> 4, li = lane & 15;

    *(float4*)&s_ch[t * 4] = *(const float4*)&s[head * N + j0 + t * 4];

    const float smx = funmap(smaxU[head]);
    float s_i[2], nmb[2];
#pragma unroll
    for (int is = 0; is < 2; ++is) {
        int row = i0 + wave * 32 + is * 16 + li;
        float sv = s[head * N + row];
        s_i[is] = sv;
        nmb[is] = -(leaky(sv + smx) + rmax[row]);
    }
    __syncthreads();

    const int jt0 = j0 >> 5;
    const unsigned short* pH = hbF + (size_t)(head * 128 + jt0) * 2048 + lane * 8;
    const unsigned short* pA = AF + (size_t)((i0 >> 7) * 128 + jt0) * 4096 + wave * 1024 + lane * 8;

    uint4 hfr[2][4], aur[2][2];
    auto loadt = [&](int tt, int b) {
        const unsigned short* ph = pH + (size_t)tt * 2048;
#pragma unroll
        for (int db = 0; db < 4; ++db) hfr[b][db] = *(const uint4*)(ph + db * 512);
        const unsigned short* pa = pA + (size_t)tt * 4096;
        aur[b][0] = *(const uint4*)pa;
        aur[b][1] = *(const uint4*)(pa + 512);
    };
    loadt(0, 0);

    f32x4 acc[2][4] = {};
    f32x4 accz[2] = {};
    bf16x8 onesb;
#pragma unroll
    for (int i = 0; i < 8; ++i) onesb[i] = 0x3F80;

#pragma unroll 4
    for (int tt = 0; tt < JC / 32; ++tt) {
        const int p = tt & 1;
        if (tt + 1 < JC / 32) loadt(tt + 1, p ^ 1);

        float4 s0 = *(const float4*)&s_ch[tt * 32 + quad * 8];
        float4 s1 = *(const float4*)&s_ch[tt * 32 + quad * 8 + 4];
        float sv[8] = {s0.x, s0.y, s0.z, s0.w, s1.x, s1.y, s1.z, s1.w};
        bf16x8 hf[4];
#pragma unroll
        for (int db = 0; db < 4; ++db) { UB u; u.u = hfr[p][db]; hf[db] = u.v; }
#pragma unroll
        for (int is = 0; is < 2; ++is) {
            unsigned auv[4] = {aur[p][is].x, aur[p][is].y, aur[p][is].z, aur[p][is].w};
            union { bf16x8 v; unsigned u[4]; } P;
            const float si = s_i[is], nm = nmb[is];
#pragma unroll
            for (int w = 0; w < 4; ++w) {
                float aLo = __uint_as_float(auv[w] << 16);
                float aHi = __uint_as_float(auv[w] & 0xffff0000u);
                float x0 = si + sv[2 * w + 0];
                float x1 = si + sv[2 * w + 1];
                float l0 = fmaxf(x0, NEG * x0);
                float l1 = fmaxf(x1, NEG * x1);
                float e0 = __expf(l0 + (aLo + nm));
                float e1 = __expf(l1 + (aHi + nm));
                unsigned r0 = __float_as_uint(e0) + 0x8000u;
                unsigned r1 = __float_as_uint(e1) + 0x8000u;
                P.u[w] = __builtin_amdgcn_perm(r1, r0, 0x07060302u);
            }
#pragma unroll
            for (int db = 0; db < 4; ++db)
                acc[is][db] = __builtin_amdgcn_mfma_f32_16x16x32_bf16(P.v, hf[db], acc[is][db], 0, 0, 0);
            accz[is] = __builtin_amdgcn_mfma_f32_16x16x32_bf16(P.v, onesb, accz[is], 0, 0, 0);
        }
    }

#pragma unroll
    for (int is = 0; is < 2; ++is) {
        int rowbase = i0 + wave * 32 + is * 16 + quad * 4;
#pragma unroll
        for (int r = 0; r < 4; ++r) {
            float* op = &out[(size_t)(rowbase + r) * OUT_F + head * D];
#pragma unroll
            for (int db = 0; db < 4; ++db) atomicAdd(&op[db * 16 + li], acc[is][db][r]);
        }
        if (li == 0) {
#pragma unroll
            for (int r = 0; r < 4; ++r) atomicAdd(&Z[head * N + rowbase + r], accz[is][r]);
        }
    }
}

// ---- K3: normalize
__global__ __launch_bounds__(256) void k_norm(float* __restrict__ out,
                                              const float* __restrict__ Z) {
    int idx = blockIdx.x * 256 + threadIdx.x;
    int i = idx >> 9, hd = idx & 511, hh = hd >> 6;
    out[idx] = out[idx] / Z[hh * N + i];
}

// ==================== FALLBACK PATH (proven R6 chain) ====================

__global__ __launch_bounds__(256, 4) void k_gemm_f(const float* __restrict__ inp,
                                                   const float* __restrict__ W,
                                                   const float* __restrict__ a_left,
                                                   unsigned short* __restrict__ hbT,
                                                   float* __restrict__ s,
                                                   unsigned* __restrict__ smaxU) {
    __shared__ float As[64][36];
    __shared__ float Bs[64][68];
    __shared__ unsigned short h_st[32][72];
    __shared__ float s_red[32];

    const int t = threadIdx.x;
    const int bi = blockIdx.x;
    const int head = blockIdx.y;
    const int iy = t >> 4, ox = t & 15;
    const int iA = t >> 3, kA = (t & 7) * 8;
    const int oB = t >> 2, kB = (t & 3) * 16;

    float4 pa[2], pb[4];
    auto loadrk = [&](int k0) {
        const float* ip = &inp[(size_t)(bi * 32 + iA) * IN_F + k0 + kA];
        const float* wp = &W[(size_t)(head * 64 + oB) * IN_F + k0 + kB];
#pragma unroll
        for (int q = 0; q < 2; ++q) pa[q] = *(const float4*)&ip[q * 4];
#pragma unroll
        for (int q = 0; q < 4; ++q) pb[q] = *(const float4*)&wp[q * 4];
    };
    loadrk(0);

    float acc[2][4] = {};
    for (int k0 = 0; k0 < IN_F; k0 += 64) {
        __syncthreads();
#pragma unroll
        for (int q = 0; q < 2; ++q)
#pragma unroll
            for (int j = 0; j < 4; ++j) As[kA + q * 4 + j][iA] = ((const float*)&pa[q])[j];
#pragma unroll
        for (int q = 0; q < 4; ++q)
#pragma unroll
            for (int j = 0; j < 4; ++j) Bs[kB + q * 4 + j][oB] = ((const float*)&pb[q])[j];
        __syncthreads();
        if (k0 + 64 < IN_F) loadrk(k0 + 64);
#pragma unroll
        for (int k = 0; k < 64; ++k) {
            float2 a2 = *(const float2*)&As[k][iy * 2];
            float4 b4 = *(const float4*)&Bs[k][ox * 4];
            float a[2] = {a2.x, a2.y};
            float b[4] = {b4.x, b4.y, b4.z, b4.w};
#pragma unroll
            for (int r = 0; r < 2; ++r)
#pragma unroll
                for (int c = 0; c < 4; ++c) acc[r][c] = fmaf(a[r], b[c], acc[r][c]);
        }
    }
    float aL[4];
#pragma unroll
    for (int c = 0; c < 4; ++c) aL[c] = a_left[head * D + ox * 4 + c];
#pragma unroll
    for (int r = 0; r < 2; ++r) {
        float sp = acc[r][0] * aL[0] + acc[r][1] * aL[1] + acc[r][2] * aL[2] + acc[r][3] * aL[3];
        sp += __shfl_xor(sp, 1); sp += __shfl_xor(sp, 2);
        sp += __shfl_xor(sp, 4); sp += __shfl_xor(sp, 8);
        if (ox == 0) {
            s[head * N + bi * 32 + iy * 2 + r] = sp;
            s_red[iy * 2 + r] = sp;
        }
    }
    __syncthreads();
    if (t < 32) {
        float m = s_red[t];
        for (int off = 16; off; off >>= 1) m = fmaxf(m, __shfl_down(m, off, 64));
        if (t == 0) atomicMax(&smaxU[head], fmap(m));
    }
#pragma unroll
    for (int r = 0; r < 2; ++r) {
        ushort4 v;
        v.x = f2bf(acc[r][0]); v.y = f2bf(acc[r][1]);
        v.z = f2bf(acc[r][2]); v.w = f2bf(acc[r][3]);
        *(ushort4*)&h_st[iy * 2 + r][ox * 4] = v;
    }
    __syncthreads();
    {
        const int d = t >> 2, iq = (t & 3) * 8;
        unsigned short us[8];
#pragma unroll
        for (int k = 0; k < 8; ++k) us[k] = h_st[iq + k][d];
        unsigned short* dst = &hbT[((size_t)(head * D + d)) * N + bi * 32 + iq];
#pragma unroll
        for (int q = 0; q < 2; ++q) {
            ushort4 v = {us[q * 4 + 0], us[q * 4 + 1], us[q * 4 + 2], us[q * 4 + 3]};
            *(ushort4*)&dst[q * 4] = v;
        }
    }
}

__global__ __launch_bounds__(256) void k_rowmax(const float* __restrict__ A,
                                                float* __restrict__ rmax) {
    int i = blockIdx.x;
    const float* row = &A[(size_t)i * N];
    float m = -1e30f;
    for (int j = threadIdx.x * 4; j < N; j += 256 * 4) {
        float4 v = *(const float4*)&row[j];
        m = fmaxf(fmaxf(fmaxf(m, v.x), fmaxf(v.y, v.z)), v.w);
    }
    for (int off = 32; off; off >>= 1) m = fmaxf(m, __shfl_down(m, off, 64));
    __shared__ float red[4];
    if ((threadIdx.x & 63) == 0) red[threadIdx.x >> 6] = m;
    __syncthreads();
    if (threadIdx.x == 0) rmax[i] = fmaxf(fmaxf(red[0], red[1]), fmaxf(red[2], red[3]));
}

#define JCF 2048
__global__ __launch_bounds__(256, 4) void k_attn_f(const float* __restrict__ A,
                                                   const unsigned short* __restrict__ hbT,
                                                   const float* __restrict__ s,
                                                   const unsigned* __restrict__ smaxU,
                                                   const float* __restrict__ rmax,
                                                   float* __restrict__ out,
                                                   float* __restrict__ Z) {
    __shared__ float A_stf[64 * 16 * 4];
    __shared__ unsigned short hT_stf[64 * 8 * 8];
    __shared__ float s_ch[JCF];

    const int t = threadIdx.x;
    const int i0 = blockIdx.x * 64;
    const int head = blockIdx.y;
    const int j0 = blockIdx.z * JCF;
    const int lane = t & 63, wave = t >> 6, quad = lane >> 4, li = lane & 15;
    const int iw = wave * 16;
    const int myrow = i0 + iw + li;

#pragma unroll
    for (int q = 0; q < 2; ++q) {
        int idx = q * 256 + t;
        *(float4*)&s_ch[idx * 4] = *(const float4*)&s[head * N + j0 + idx * 4];
    }
    const float s_i = s[head * N + myrow];
    const float mb = leaky(s_i + funmap(smaxU[head])) + rmax[myrow];

    const float* gA[4]; void* lA[4];
#pragma unroll
    for (int q = 0; q < 4; ++q) {
        int slot = q * 256 + t;
        int r = slot >> 4, c4p = slot & 15;
        int c4 = c4p ^ (r & 7);
        gA[q] = &A[(size_t)(i0 + r) * N + j0 + c4 * 4];
        lA[q] = (void*)&A_stf[slot * 4];
    }
    const unsigned short* gH[2]; void* lH[2];
#pragma unroll
    for (int q = 0; q < 2; ++q) {
        int slot = q * 256 + t;
        int r = slot >> 3, u = slot & 7;
        int uc = u ^ (r & 7);
        gH[q] = &hbT[(size_t)head * D * N + (size_t)r * N + j0 + uc * 8];
        lH[q] = (void*)&hT_stf[slot * 8];
    }

    f32x4 acc[4] = {{0, 0, 0, 0}, {0, 0, 0, 0}, {0, 0, 0, 0}, {0, 0, 0, 0}};
    float zsum = 0.f;

    for (int jt = 0; jt < JCF; jt += 64) {
        __syncthreads();
#pragma unroll
        for (int q = 0; q < 4; ++q) dma16(gA[q] + jt, lA[q]);
#pragma unroll
        for (int q = 0; q < 2; ++q) dma16(gH[q] + jt, lH[q]);
        __syncthreads();

#pragma unroll
        for (int kh = 0; kh < 2; ++kh) {
            const int u0 = kh * 8 + quad * 2;
            const int sw = li & 7;
            float4 a0 = *(const float4*)&A_stf[((iw + li) * 16 + (u0 ^ sw)) * 4];
            float4 a1 = *(const float4*)&A_stf[((iw + li) * 16 + ((u0 + 1) ^ sw)) * 4];
            const int jl = kh * 32 + quad * 8;
            float4 s0 = *(const float4*)&s_ch[jt + jl];
            float4 s1 = *(const float4*)&s_ch[jt + jl + 4];
            float av[8] = {a0.x, a0.y, a0.z, a0.w, a1.x, a1.y, a1.z, a1.w};
            float sv[8] = {s0.x, s0.y, s0.z, s0.w, s1.x, s1.y, s1.z, s1.w};
            union { bf16x8 v; unsigned u[4]; } P;
#pragma unroll
            for (int p = 0; p < 4; ++p) {
                float x0 = s_i + sv[2 * p + 0];
                float x1 = s_i + sv[2 * p + 1];
                float w0 = __expf(fmaxf(x0, NEG * x0) + (av[2 * p + 0] - mb));
                float w1 = __expf(fmaxf(x1, NEG * x1) + (av[2 * p + 1] - mb));
                zsum += w0 + w1;
                P.u[p] = ((unsigned)f2bf(w1) << 16) | (unsigned)f2bf(w0);
            }
#pragma unroll
            for (int db = 0; db < 4; ++db) {
                int slotH = (db * 16 + li) * 8 + ((kh * 4 + quad) ^ sw);
                bf16x8 hf = *(const bf16x8*)&hT_stf[slotH * 8];
                acc[db] = __builtin_amdgcn_mfma_f32_16x16x32_bf16(P.v, hf, acc[db], 0, 0, 0);
            }
        }
    }

    zsum += __shfl_xor(zsum, 16);
    zsum += __shfl_xor(zsum, 32);
    if (quad == 0) atomicAdd(&Z[head * N + myrow], zsum);

#pragma unroll
    for (int r = 0; r < 4; ++r) {
        float* op = &out[(size_t)(i0 + iw + quad * 4 + r) * OUT_F + head * D];
#pragma unroll
        for (int db = 0; db < 4; ++db) atomicAdd(&op[db * 16 + li], acc[db][r]);
    }
}

// ==================== launcher ====================

extern "C" void kernel_launch(void* const* d_in, const int* in_sizes, int n_in,
                              void* d_out, int out_size, void* d_ws, size_t ws_size,
                              hipStream_t stream) {
    const float* inp = (const float*)d_in[0];
    const float* A = (const float*)d_in[1];
    const float* W = (const float*)d_in[2];
    const float* a_left = (const float*)d_in[3];
    float* out = (float*)d_out;

    // ws: hbF 4M | @4M iFH 2M | @6M iFL 2M | @8M WFH 256K | WFL 256K |
    //     @8.5M s 128K | Z 128K | @8.75M smaxU 32B | +4K rmax 16K | @10M AF 32M
    char* base = (char*)d_ws;
    unsigned short* hbF = (unsigned short*)base;
    unsigned short* iFH = (unsigned short*)(base + ((size_t)4 << 20));
    unsigned short* iFL = (unsigned short*)(base + ((size_t)6 << 20));
    unsigned short* WFH = (unsigned short*)(base + ((size_t)8 << 20));
    unsigned short* WFL = (unsigned short*)(base + ((size_t)8 << 20) + ((size_t)256 << 10));
    float* s = (float*)(base + ((size_t)8 << 20) + ((size_t)512 << 10));
    float* Z = s + (size_t)H * N;
    unsigned* smaxU = (unsigned*)(Z + (size_t)H * N);
    float* rmax = (float*)(base + ((size_t)8 << 20) + ((size_t)512 << 10) + ((size_t)260 << 10));
    unsigned short* AF = (unsigned short*)(base + ((size_t)10 << 20));
    const bool big = ws_size >= (((size_t)10 << 20) + (size_t)N * N * 2);

    hipMemsetAsync(out, 0, (size_t)N * OUT_F * sizeof(float), stream);
    hipMemsetAsync(Z, 0, (size_t)H * N * sizeof(float) + 8 * sizeof(unsigned), stream);

    if (big) {
        k_prep<<<dim3(N), 256, 0, stream>>>(A, inp, W, AF, rmax, iFH, iFL, WFH, WFL);
        k_gemm<<<dim3(N / 64, H), 256, 0, stream>>>(iFH, iFL, WFH, WFL, a_left, hbF, s, smaxU);
        k_attn<<<dim3(N / 128, H, N / JC), 256, 0, stream>>>(AF, hbF, s, smaxU, rmax, out, Z);
    } else {
        k_gemm_f<<<dim3(N / 32, H), 256, 0, stream>>>(inp, W, a_left, hbF, s, smaxU);
        k_rowmax<<<dim3(N), 256, 0, stream>>>(A, rmax);
        k_attn_f<<<dim3(N / 64, H, N / JCF), 256, 0, stream>>>(A, hbF, s, smaxU, rmax, out, Z);
    }
    k_norm<<<dim3(N * OUT_F / 256), 256, 0, stream>>>(out, Z);
}